// Round 13
// baseline (222.687 us; speedup 1.0000x reference)
//
#include <hip/hip_runtime.h>
#include <hip/hip_bf16.h>
#include <math.h>

typedef short bf16x8 __attribute__((ext_vector_type(8)));
typedef float f32x4  __attribute__((ext_vector_type(4)));

struct WC   { float c[13]; };                 // interior composed 13-tap
struct G157 { float g3[3], g5[5], g7[7]; };   // per-level 1-D gaussians

__device__ __forceinline__ unsigned short f2bf(float f) {
  __hip_bfloat16 h = __float2bfloat16(f);     // RNE
  return *reinterpret_cast<unsigned short*>(&h);
}

// zero out + S; block 0 builds per-position composed weight table wtab[256][16]
__global__ __launch_bounds__(256) void zero_k(float* __restrict__ out, float* __restrict__ S,
                                              float* __restrict__ wtab, G157 gw) {
  int i = blockIdx.x * 256 + threadIdx.x;
  if (i < 65536) out[i] = 0.f;
  if (i < 1024) S[i] = 0.f;
  if (blockIdx.x == 0) {
    int g = threadIdx.x;
    float row[13];
    #pragma unroll
    for (int t = 0; t < 13; ++t) row[t] = 0.f;
    #pragma unroll
    for (int di = -3; di <= 3; ++di) {
      int ii = g + di;
      if ((unsigned)ii >= 256u) continue;
      float w7 = gw.g7[di + 3];
      #pragma unroll
      for (int dj = -2; dj <= 2; ++dj) {
        int jj = ii + dj;
        if ((unsigned)jj >= 256u) continue;
        float c2 = w7 * gw.g5[dj + 2];
        #pragma unroll
        for (int dk = -1; dk <= 1; ++dk) {
          int mm = jj + dk;
          if ((unsigned)mm >= 256u) continue;
          row[di + dj + dk + 6] += c2 * gw.g3[dk + 1];
        }
      }
    }
    #pragma unroll
    for (int t = 0; t < 13; ++t) wtab[(g << 4) + t] = row[t];
    wtab[(g << 4) + 13] = 0.f; wtab[(g << 4) + 14] = 0.f; wtab[(g << 4) + 15] = 0.f;
  }
}

// ctx = x - blur(x), bf16 out. One wave = one full 256-col row (lane q: cols 4q..4q+3).
// 16-row sweep; x rows in a NAMED-register ring (16 float4 vars, macro-rotated — no
// array indexing, no scratch); v-conv in regs; v->h halo via 12 lane shuffles (no LDS,
// no barriers in the loop). Edge cols via evs capture + wave-local exact post-pass.
__global__ __launch_bounds__(256, 4) void ctx_k(const float* __restrict__ x,
                                                unsigned short* __restrict__ ctxb,
                                                const float* __restrict__ wtab,
                                                WC wc) {
  __shared__ __align__(16) float evs[4][16][24];  // per-wave v at cols 0..11/244..255
  __shared__ float wl[96];                        // boundary weight rows 0..5 (x16)

  const int tid = threadIdx.x;
  const int wid = tid >> 6, q = tid & 63;
  const int img = blockIdx.x >> 2, band = blockIdx.x & 3;
  const int r0 = (band << 6) + (wid << 4);   // this wave's 16 rows
  const int c0 = q << 2;
  const float* xg = x + ((size_t)img << 16);
  unsigned short* cgb = ctxb + ((size_t)img << 16);

  if (tid < 96) wl[tid] = wtab[tid];
  __syncthreads();  // wl visibility only

  const int qm2 = (q < 2) ? 0 : (q - 2);
  const int qm1 = (q < 1) ? 0 : (q - 1);
  const int qp1 = (q > 62) ? 63 : (q + 1);
  const int qp2 = (q > 61) ? 63 : (q + 2);

  // named register ring: slot i holds row r0-6+i (mod 16 rotation via macro args)
  float4 g0,g1,g2,g3,g4,g5,g6,g7,g8,g9,g10,g11,g12,g13,g14,g15;
#define LDR(i) { int yy_ = r0 - 6 + (i); g##i = make_float4(0.f,0.f,0.f,0.f); \
                 if ((unsigned)yy_ < 256u) g##i = *(const float4*)(xg + yy_ * 256 + c0); }
  LDR(0) LDR(1) LDR(2) LDR(3) LDR(4) LDR(5) LDR(6) LDR(7)
  LDR(8) LDR(9) LDR(10) LDR(11) LDR(12) LDR(13) LDR(14)
#undef LDR
  g15 = make_float4(0.f, 0.f, 0.f, 0.f);

#define WINT(t, s) { float wv_ = wc.c[t]; ax += wv_*(s).x; ay += wv_*(s).y; az += wv_*(s).z; aw += wv_*(s).w; }
#define WTOP(t, s) { float wv_ = wl[(y << 4) + (t)]; ax += wv_*(s).x; ay += wv_*(s).y; az += wv_*(s).z; aw += wv_*(s).w; }
#define WBOT(t, s) { float wv_ = wl[((255 - y) << 4) + (12 - (t))]; ax += wv_*(s).x; ay += wv_*(s).y; az += wv_*(s).z; aw += wv_*(s).w; }
#define VALLW(M, s0,s1,s2,s3,s4,s5,s6,s7,s8,s9,s10,s11,s12) \
  M(0,s0) M(1,s1) M(2,s2) M(3,s3) M(4,s4) M(5,s5) M(6,s6) \
  M(7,s7) M(8,s8) M(9,s9) M(10,s10) M(11,s11) M(12,s12)

#define STEP(R, s0,s1,s2,s3,s4,s5,s6,s7,s8,s9,s10,s11,s12,s13,s14,s15) { \
  if ((R) <= 12) { \
    int yy_ = r0 + (R) + 9; \
    float4 nv_ = make_float4(0.f,0.f,0.f,0.f); \
    if (yy_ < 256) nv_ = *(const float4*)(xg + yy_ * 256 + c0); \
    s15 = nv_; \
  } \
  const int y = r0 + (R); \
  float ax = 0.f, ay = 0.f, az = 0.f, aw = 0.f; \
  if ((R) >= 6 && (R) <= 9) { \
    VALLW(WINT, s0,s1,s2,s3,s4,s5,s6,s7,s8,s9,s10,s11,s12) \
  } else if ((R) < 6) { \
    if (y >= 6) { VALLW(WINT, s0,s1,s2,s3,s4,s5,s6,s7,s8,s9,s10,s11,s12) } \
    else        { VALLW(WTOP, s0,s1,s2,s3,s4,s5,s6,s7,s8,s9,s10,s11,s12) } \
  } else { \
    if (y <= 249) { VALLW(WINT, s0,s1,s2,s3,s4,s5,s6,s7,s8,s9,s10,s11,s12) } \
    else          { VALLW(WBOT, s0,s1,s2,s3,s4,s5,s6,s7,s8,s9,s10,s11,s12) } \
  } \
  if (q < 3)       *(float4*)&evs[wid][R][c0] = make_float4(ax, ay, az, aw); \
  else if (q >= 61) *(float4*)&evs[wid][R][12 + ((q - 61) << 2)] = make_float4(ax, ay, az, aw); \
  float W[16]; \
  W[0] = __shfl(az, qm2); W[1] = __shfl(aw, qm2); \
  W[2] = __shfl(ax, qm1); W[3] = __shfl(ay, qm1); W[4] = __shfl(az, qm1); W[5] = __shfl(aw, qm1); \
  W[6] = ax; W[7] = ay; W[8] = az; W[9] = aw; \
  W[10] = __shfl(ax, qp1); W[11] = __shfl(ay, qp1); W[12] = __shfl(az, qp1); W[13] = __shfl(aw, qp1); \
  W[14] = __shfl(ax, qp2); W[15] = __shfl(ay, qp2); \
  float h0 = 0.f, h1 = 0.f, h2 = 0.f, h3 = 0.f; \
  _Pragma("unroll") \
  for (int t = 0; t < 13; ++t) { \
    float wv_ = wc.c[t]; \
    h0 += wv_ * W[t]; h1 += wv_ * W[t + 1]; h2 += wv_ * W[t + 2]; h3 += wv_ * W[t + 3]; \
  } \
  float4 xq_ = s6; \
  unsigned short t0_ = f2bf(xq_.x - h0), t1_ = f2bf(xq_.y - h1); \
  unsigned short t2_ = f2bf(xq_.z - h2), t3_ = f2bf(xq_.w - h3); \
  *(ushort4*)(cgb + (size_t)y * 256 + c0) = make_ushort4(t0_, t1_, t2_, t3_); \
}

  STEP(0,  g0,g1,g2,g3,g4,g5,g6,g7,g8,g9,g10,g11,g12,g13,g14,g15)
  STEP(1,  g1,g2,g3,g4,g5,g6,g7,g8,g9,g10,g11,g12,g13,g14,g15,g0)
  STEP(2,  g2,g3,g4,g5,g6,g7,g8,g9,g10,g11,g12,g13,g14,g15,g0,g1)
  STEP(3,  g3,g4,g5,g6,g7,g8,g9,g10,g11,g12,g13,g14,g15,g0,g1,g2)
  STEP(4,  g4,g5,g6,g7,g8,g9,g10,g11,g12,g13,g14,g15,g0,g1,g2,g3)
  STEP(5,  g5,g6,g7,g8,g9,g10,g11,g12,g13,g14,g15,g0,g1,g2,g3,g4)
  STEP(6,  g6,g7,g8,g9,g10,g11,g12,g13,g14,g15,g0,g1,g2,g3,g4,g5)
  STEP(7,  g7,g8,g9,g10,g11,g12,g13,g14,g15,g0,g1,g2,g3,g4,g5,g6)
  STEP(8,  g8,g9,g10,g11,g12,g13,g14,g15,g0,g1,g2,g3,g4,g5,g6,g7)
  STEP(9,  g9,g10,g11,g12,g13,g14,g15,g0,g1,g2,g3,g4,g5,g6,g7,g8)
  STEP(10, g10,g11,g12,g13,g14,g15,g0,g1,g2,g3,g4,g5,g6,g7,g8,g9)
  STEP(11, g11,g12,g13,g14,g15,g0,g1,g2,g3,g4,g5,g6,g7,g8,g9,g10)
  STEP(12, g12,g13,g14,g15,g0,g1,g2,g3,g4,g5,g6,g7,g8,g9,g10,g11)
  STEP(13, g13,g14,g15,g0,g1,g2,g3,g4,g5,g6,g7,g8,g9,g10,g11,g12)
  STEP(14, g14,g15,g0,g1,g2,g3,g4,g5,g6,g7,g8,g9,g10,g11,g12,g13)
  STEP(15, g15,g0,g1,g2,g3,g4,g5,g6,g7,g8,g9,g10,g11,g12,g13,g14)
#undef STEP
#undef VALLW
#undef WINT
#undef WTOP
#undef WBOT

  // wave-local post-pass: exact h at the 12 edge cols x this wave's 16 rows.
  #pragma unroll
  for (int k = 0; k < 3; ++k) {
    int e = (k << 6) + q;              // 0..191 = 16 rows x 12 cols
    int row = e / 12;
    int ce = e - row * 12;
    int y = r0 + row;
    int col = (ce < 6) ? ce : (244 + ce);   // {0..5, 250..255}
    float h = 0.f;
    if (ce < 6) {
      #pragma unroll
      for (int t = 0; t < 13; ++t) {
        int vc = col - 6 + t;
        int vi = (vc < 0) ? 0 : vc;         // weight is 0 when vc<0
        h += wl[(col << 4) + t] * evs[wid][row][vi];
      }
    } else {
      #pragma unroll
      for (int t = 0; t < 13; ++t) {
        int vc = col - 6 + t;
        int vi = (vc > 255 ? 255 : vc) - 232;  // weight is 0 when vc>255
        h += wl[((255 - col) << 4) + (12 - t)] * evs[wid][row][vi];
      }
    }
    float xv = xg[(size_t)y * 256 + col];
    cgb[(size_t)y * 256 + col] = f2bf(xv - h);
  }
}

// MFMA att: per batch b, att = P * C^T, P = exp(C), C = ctx[b] (64 x 65536 bf16).
// S[b,d] accumulated here (each ctx element seen exactly once as an A-fragment).
__global__ __launch_bounds__(256) void att_k(const unsigned short* __restrict__ ctxb,
                                             float* __restrict__ S,
                                             float* __restrict__ attacc) {
  const int t = threadIdx.x;
  const int wv = t >> 6, lane = t & 63;
  const int rw = lane & 15;
  const int kq = lane >> 4;
  const int ci = blockIdx.x;       // 64 chunks of 1024
  const int b = blockIdx.y;        // 16 batches
  const unsigned short* cb = ctxb + ((size_t)b << 22);
  const int n0 = (ci << 10) + (kq << 3);

  const unsigned short* pA = cb + (((size_t)(16 * wv + rw)) << 16) + n0;
  const unsigned short* pB = cb + (((size_t)rw) << 16) + n0;

  f32x4 acc0 = {0.f, 0.f, 0.f, 0.f}, acc1 = acc0, acc2 = acc0, acc3 = acc0;
  float ssum = 0.f;

  #pragma unroll 8
  for (int ks = 0; ks < 1024; ks += 32) {
    bf16x8 av = *(const bf16x8*)(pA + ks);
    bf16x8 ev;
    const unsigned* au = (const unsigned*)&av;
    unsigned* eu = (unsigned*)&ev;
    #pragma unroll
    for (int j = 0; j < 4; ++j) {
      unsigned ww = au[j];
      float elo = __expf(__uint_as_float(ww << 16));
      float ehi = __expf(__uint_as_float(ww & 0xffff0000u));
      ssum += elo + ehi;
      eu[j] = ((unsigned)f2bf(ehi) << 16) | (unsigned)f2bf(elo);
    }
    bf16x8 b0 = *(const bf16x8*)(pB + ks);
    bf16x8 b1 = *(const bf16x8*)(pB + (size_t)(16 << 16) + ks);
    bf16x8 b2 = *(const bf16x8*)(pB + (size_t)(32 << 16) + ks);
    bf16x8 b3 = *(const bf16x8*)(pB + (size_t)(48 << 16) + ks);
    acc0 = __builtin_amdgcn_mfma_f32_16x16x32_bf16(ev, b0, acc0, 0, 0, 0);
    acc1 = __builtin_amdgcn_mfma_f32_16x16x32_bf16(ev, b1, acc1, 0, 0, 0);
    acc2 = __builtin_amdgcn_mfma_f32_16x16x32_bf16(ev, b2, acc2, 0, 0, 0);
    acc3 = __builtin_amdgcn_mfma_f32_16x16x32_bf16(ev, b3, acc3, 0, 0, 0);
  }

  // S row-sum: lanes {rw, rw+16, rw+32, rw+48} hold partials for row 16wv+rw
  ssum += __shfl_xor(ssum, 16);
  ssum += __shfl_xor(ssum, 32);
  if (lane < 16) atomicAdd(&S[(b << 6) + (wv << 4) + rw], ssum);

  // C/D layout: col = lane&15, row = (lane>>4)*4 + reg
  const int dl = kq << 2;
  float* ap = attacc + (((size_t)((b << 6) + (wv << 4) + dl)) << 6) + rw;
  #pragma unroll
  for (int reg = 0; reg < 4; ++reg) {
    atomicAdd(ap + ((size_t)reg << 6) + 0,  acc0[reg]);
    atomicAdd(ap + ((size_t)reg << 6) + 16, acc1[reg]);
    atomicAdd(ap + ((size_t)reg << 6) + 32, acc2[reg]);
    atomicAdd(ap + ((size_t)reg << 6) + 48, acc3[reg]);
  }
}

__global__ __launch_bounds__(256) void fin_k(float* __restrict__ out, const float* __restrict__ S) {
  int i = blockIdx.x * 256 + threadIdx.x;  // 65536 = 16*64*64
  out[i] = out[i] / S[i >> 6];
}

extern "C" void kernel_launch(void* const* d_in, const int* in_sizes, int n_in,
                              void* d_out, int out_size, void* d_ws, size_t ws_size,
                              hipStream_t stream) {
  const float* x = (const float*)d_in[0];
  float* out = (float*)d_out;
  unsigned short* ctxb = (unsigned short*)d_ws;                        // 134 MiB bf16
  float* S    = (float*)((char*)d_ws + (size_t)67108864 * 2);          // 4 KB
  float* wtab = (float*)((char*)d_ws + (size_t)67108864 * 2 + 4096);   // 16 KB
  if (ws_size < (size_t)67108864 * 2 + 4096 + 16384) return;

  // per-level 1-D gaussians in double (matches cv2.getGaussianKernel)
  double gg[3][7];
  double sv = pow(2.0, 1.0 / 3.0);
  for (int lv = 0; lv < 3; ++lv) {
    int k = 2 * lv + 3;
    double sig = 1.6 * pow(sv, lv), sum = 0.0;
    for (int i = 0; i < k; ++i) {
      double a = i - (k - 1) / 2.0;
      gg[lv][i] = exp(-a * a / (2.0 * sig * sig));
      sum += gg[lv][i];
    }
    for (int i = 0; i < k; ++i) gg[lv][i] /= sum;
  }

  G157 gw;
  for (int i = 0; i < 3; ++i) gw.g3[i] = (float)gg[0][i];
  for (int i = 0; i < 5; ++i) gw.g5[i] = (float)gg[1][i];
  for (int i = 0; i < 7; ++i) gw.g7[i] = (float)gg[2][i];

  WC wc;
  {
    double t35[7] = {0};
    for (int i = 0; i < 3; ++i)
      for (int j = 0; j < 5; ++j) t35[i + j] += gg[0][i] * gg[1][j];
    double t357[13] = {0};
    for (int i = 0; i < 7; ++i)
      for (int j = 0; j < 7; ++j) t357[i + j] += t35[i] * gg[2][j];
    for (int t = 0; t < 13; ++t) wc.c[t] = (float)t357[t];
  }

  zero_k<<<dim3(256), dim3(256), 0, stream>>>(out, S, wtab, gw);
  ctx_k<<<dim3(4096), dim3(256), 0, stream>>>(x, ctxb, wtab, wc);
  att_k<<<dim3(64, 16), dim3(256), 0, stream>>>(ctxb, S, out);
  fin_k<<<dim3(256), dim3(256), 0, stream>>>(out, S);
}

// Round 14
// 187.491 us; speedup vs baseline: 1.1877x; 1.1877x over previous
//
#include <hip/hip_runtime.h>
#include <hip/hip_bf16.h>
#include <math.h>

typedef short bf16x8 __attribute__((ext_vector_type(8)));
typedef float f32x4  __attribute__((ext_vector_type(4)));

struct WC   { float c[13]; };                 // interior composed 13-tap
struct G157 { float g3[3], g5[5], g7[7]; };   // per-level 1-D gaussians

__device__ __forceinline__ unsigned short f2bf(float f) {
  __hip_bfloat16 h = __float2bfloat16(f);     // RNE
  return *reinterpret_cast<unsigned short*>(&h);
}

// zero out + S; block 0 builds per-position composed weight table wtab[256][16]
__global__ __launch_bounds__(256) void zero_k(float* __restrict__ out, float* __restrict__ S,
                                              float* __restrict__ wtab, G157 gw) {
  int i = blockIdx.x * 256 + threadIdx.x;
  if (i < 65536) out[i] = 0.f;
  if (i < 1024) S[i] = 0.f;
  if (blockIdx.x == 0) {
    int g = threadIdx.x;
    float row[13];
    #pragma unroll
    for (int t = 0; t < 13; ++t) row[t] = 0.f;
    #pragma unroll
    for (int di = -3; di <= 3; ++di) {
      int ii = g + di;
      if ((unsigned)ii >= 256u) continue;
      float w7 = gw.g7[di + 3];
      #pragma unroll
      for (int dj = -2; dj <= 2; ++dj) {
        int jj = ii + dj;
        if ((unsigned)jj >= 256u) continue;
        float c2 = w7 * gw.g5[dj + 2];
        #pragma unroll
        for (int dk = -1; dk <= 1; ++dk) {
          int mm = jj + dk;
          if ((unsigned)mm >= 256u) continue;
          row[di + dj + dk + 6] += c2 * gw.g3[dk + 1];
        }
      }
    }
    #pragma unroll
    for (int t = 0; t < 13; ++t) wtab[(g << 4) + t] = row[t];
    wtab[(g << 4) + 13] = 0.f; wtab[(g << 4) + 14] = 0.f; wtab[(g << 4) + 15] = 0.f;
  }
}

// ctx = x - blur(x), bf16 out. Round-8 structure (proven best) with SINGLE-buffered
// rb/xrb + two barriers per iteration: LDS 23.5->15 KB => 8 blocks/CU resident.
__global__ __launch_bounds__(256) void ctx_k(const float* __restrict__ x,
                                             unsigned short* __restrict__ ctxb,
                                             const float* __restrict__ wtab,
                                             WC wc) {
  __shared__ __align__(16) float rb[4][272];   // v-results: 8 pad | 256 | 8 pad
  __shared__ __align__(16) float xrb[4][256];  // x rows (for ctx = x - h)
  __shared__ float vs[64][24];                 // v-results at cols 0..11 / 244..255
  __shared__ float wl[96];                     // boundary weight rows 0..5 (x16)

  const int tid = threadIdx.x;
  const int img = blockIdx.x >> 2;
  const int band = blockIdx.x & 3;
  const int y0 = band << 6;
  const float* xg = x + ((size_t)img << 16);
  unsigned short* cgb = ctxb + ((size_t)img << 16);

  if (tid < 96) wl[tid] = wtab[tid];
  if (tid < 64) {  // zero rb pads once: 4 rows x 16 pad
    int rr = tid >> 4, pp = tid & 15;
    rb[rr][(pp < 8) ? pp : (256 + pp)] = 0.f;
  }

  // input ring: slot(row) = (row - y0 + 6) mod 24. Init rows y0-6 .. y0+13.
  float win[24];
  #pragma unroll
  for (int i = 0; i < 24; ++i) win[i] = 0.f;
  #pragma unroll
  for (int i = 0; i < 20; ++i) {
    int yy = y0 - 6 + i;
    if ((unsigned)yy < 256u) win[i] = xg[yy * 256 + tid];
  }
  __syncthreads();

  const bool vsave = (tid < 12) || (tid >= 244);
  const int vsidx = (tid < 12) ? tid : (tid - 232);
  const int g = tid >> 6, q = tid & 63;   // h-phase: wave g -> row, lane q -> cols 4q..4q+3

  #pragma unroll
  for (int it = 0; it < 16; ++it) {
    const int y = y0 + 4 * it;
    // prefetch rows y+14..y+17 (2-iteration lookahead); band needs rows up to y0+69
    #pragma unroll
    for (int j = 0; j < 4; ++j) {
      if (4 * it + 14 + j < 70) {
        int yy = y + 14 + j;
        float v = 0.f;
        if (yy < 256) v = xg[yy * 256 + tid];
        win[(4 * it + 20 + j) % 24] = v;
      }
    }
    // vertical conv, 4 rows, per-column (compile-time ring indices)
    float vv[4];
    if (it > 1 && it < 14) {  // rows y0+8..y0+55: always interior
      #pragma unroll
      for (int r = 0; r < 4; ++r) {
        float a = 0.f;
        #pragma unroll
        for (int t = 0; t < 13; ++t) a += wc.c[t] * win[(4 * it + r + t) % 24];
        vv[r] = a;
      }
    } else {
      #pragma unroll
      for (int r = 0; r < 4; ++r) {
        int yr = y + r;
        float a = 0.f;
        if (yr < 6) {
          #pragma unroll
          for (int t = 0; t < 13; ++t) a += wl[(yr << 4) + t] * win[(4 * it + r + t) % 24];
        } else if (yr > 249) {
          #pragma unroll
          for (int t = 0; t < 13; ++t) a += wl[((255 - yr) << 4) + (12 - t)] * win[(4 * it + r + t) % 24];
        } else {
          #pragma unroll
          for (int t = 0; t < 13; ++t) a += wc.c[t] * win[(4 * it + r + t) % 24];
        }
        vv[r] = a;
      }
    }
    #pragma unroll
    for (int r = 0; r < 4; ++r) {
      rb[r][8 + tid] = vv[r];
      xrb[r][tid] = win[(4 * it + 6 + r) % 24];
    }
    if (vsave) {
      #pragma unroll
      for (int r = 0; r < 4; ++r) vs[4 * it + r][vsidx] = vv[r];
    }
    __syncthreads();

    // horizontal conv: aligned b128 reads; cols 4q+j use f[2+j .. 14+j]
    const float* hp = &rb[g][4 * q];
    float f[20];
    *(float4*)&f[0]  = *(const float4*)(hp + 0);
    *(float4*)&f[4]  = *(const float4*)(hp + 4);
    *(float4*)&f[8]  = *(const float4*)(hp + 8);
    *(float4*)&f[12] = *(const float4*)(hp + 12);
    *(float4*)&f[16] = *(const float4*)(hp + 16);
    float4 xq = *(const float4*)&xrb[g][4 * q];
    float h0 = 0.f, h1 = 0.f, h2 = 0.f, h3 = 0.f;
    #pragma unroll
    for (int t = 0; t < 13; ++t) {
      float w = wc.c[t];
      h0 += w * f[2 + t]; h1 += w * f[3 + t]; h2 += w * f[4 + t]; h3 += w * f[5 + t];
    }
    unsigned short s0 = f2bf(xq.x - h0), s1 = f2bf(xq.y - h1);
    unsigned short s2 = f2bf(xq.z - h2), s3 = f2bf(xq.w - h3);
    *(ushort4*)(cgb + (size_t)(y + g) * 256 + 4 * q) = make_ushort4(s0, s1, s2, s3);
    __syncthreads();   // protect single rb/xrb buffer before next iteration's writes
  }

  // post-pass: exact h-conv for 12 edge cols x 64 rows from saved v-results
  #pragma unroll
  for (int k = 0; k < 3; ++k) {
    int e = k * 256 + tid;           // 768 elements
    int row = e / 12;
    int ce = e - row * 12;
    int col = (ce < 6) ? ce : (244 + ce);   // {0..5, 250..255}
    float h = 0.f;
    if (ce < 6) {
      #pragma unroll
      for (int t = 0; t < 13; ++t) {
        int vc = col - 6 + t;
        if (vc >= 0) h += wl[(col << 4) + t] * vs[row][vc];
      }
    } else {
      #pragma unroll
      for (int t = 0; t < 13; ++t) {
        int vc = col - 6 + t;
        if (vc < 256) h += wl[((255 - col) << 4) + (12 - t)] * vs[row][vc - 232];
      }
    }
    int yrow = y0 + row;
    float xval = xg[yrow * 256 + col];
    cgb[yrow * 256 + col] = f2bf(xval - h);
  }
}

// MFMA att: per batch b, att = P * C^T, P = exp(C), C = ctx[b] (64 x 65536 bf16).
// S[b,d] accumulated here (each ctx element seen exactly once as an A-fragment).
__global__ __launch_bounds__(256) void att_k(const unsigned short* __restrict__ ctxb,
                                             float* __restrict__ S,
                                             float* __restrict__ attacc) {
  const int t = threadIdx.x;
  const int wv = t >> 6, lane = t & 63;
  const int rw = lane & 15;
  const int kq = lane >> 4;
  const int ci = blockIdx.x;       // 64 chunks of 1024
  const int b = blockIdx.y;        // 16 batches
  const unsigned short* cb = ctxb + ((size_t)b << 22);
  const int n0 = (ci << 10) + (kq << 3);

  const unsigned short* pA = cb + (((size_t)(16 * wv + rw)) << 16) + n0;
  const unsigned short* pB = cb + (((size_t)rw) << 16) + n0;

  f32x4 acc0 = {0.f, 0.f, 0.f, 0.f}, acc1 = acc0, acc2 = acc0, acc3 = acc0;
  float ssum = 0.f;

  #pragma unroll 8
  for (int ks = 0; ks < 1024; ks += 32) {
    bf16x8 av = *(const bf16x8*)(pA + ks);
    bf16x8 ev;
    const unsigned* au = (const unsigned*)&av;
    unsigned* eu = (unsigned*)&ev;
    #pragma unroll
    for (int j = 0; j < 4; ++j) {
      unsigned ww = au[j];
      float elo = __expf(__uint_as_float(ww << 16));
      float ehi = __expf(__uint_as_float(ww & 0xffff0000u));
      ssum += elo + ehi;
      eu[j] = ((unsigned)f2bf(ehi) << 16) | (unsigned)f2bf(elo);
    }
    bf16x8 b0 = *(const bf16x8*)(pB + ks);
    bf16x8 b1 = *(const bf16x8*)(pB + (size_t)(16 << 16) + ks);
    bf16x8 b2 = *(const bf16x8*)(pB + (size_t)(32 << 16) + ks);
    bf16x8 b3 = *(const bf16x8*)(pB + (size_t)(48 << 16) + ks);
    acc0 = __builtin_amdgcn_mfma_f32_16x16x32_bf16(ev, b0, acc0, 0, 0, 0);
    acc1 = __builtin_amdgcn_mfma_f32_16x16x32_bf16(ev, b1, acc1, 0, 0, 0);
    acc2 = __builtin_amdgcn_mfma_f32_16x16x32_bf16(ev, b2, acc2, 0, 0, 0);
    acc3 = __builtin_amdgcn_mfma_f32_16x16x32_bf16(ev, b3, acc3, 0, 0, 0);
  }

  // S row-sum: lanes {rw, rw+16, rw+32, rw+48} hold partials for row 16wv+rw
  ssum += __shfl_xor(ssum, 16);
  ssum += __shfl_xor(ssum, 32);
  if (lane < 16) atomicAdd(&S[(b << 6) + (wv << 4) + rw], ssum);

  // C/D layout: col = lane&15, row = (lane>>4)*4 + reg
  const int dl = kq << 2;
  float* ap = attacc + (((size_t)((b << 6) + (wv << 4) + dl)) << 6) + rw;
  #pragma unroll
  for (int reg = 0; reg < 4; ++reg) {
    atomicAdd(ap + ((size_t)reg << 6) + 0,  acc0[reg]);
    atomicAdd(ap + ((size_t)reg << 6) + 16, acc1[reg]);
    atomicAdd(ap + ((size_t)reg << 6) + 32, acc2[reg]);
    atomicAdd(ap + ((size_t)reg << 6) + 48, acc3[reg]);
  }
}

__global__ __launch_bounds__(256) void fin_k(float* __restrict__ out, const float* __restrict__ S) {
  int i = blockIdx.x * 256 + threadIdx.x;  // 65536 = 16*64*64
  out[i] = out[i] / S[i >> 6];
}

extern "C" void kernel_launch(void* const* d_in, const int* in_sizes, int n_in,
                              void* d_out, int out_size, void* d_ws, size_t ws_size,
                              hipStream_t stream) {
  const float* x = (const float*)d_in[0];
  float* out = (float*)d_out;
  unsigned short* ctxb = (unsigned short*)d_ws;                        // 134 MiB bf16
  float* S    = (float*)((char*)d_ws + (size_t)67108864 * 2);          // 4 KB
  float* wtab = (float*)((char*)d_ws + (size_t)67108864 * 2 + 4096);   // 16 KB
  if (ws_size < (size_t)67108864 * 2 + 4096 + 16384) return;

  // per-level 1-D gaussians in double (matches cv2.getGaussianKernel)
  double gg[3][7];
  double sv = pow(2.0, 1.0 / 3.0);
  for (int lv = 0; lv < 3; ++lv) {
    int k = 2 * lv + 3;
    double sig = 1.6 * pow(sv, lv), sum = 0.0;
    for (int i = 0; i < k; ++i) {
      double a = i - (k - 1) / 2.0;
      gg[lv][i] = exp(-a * a / (2.0 * sig * sig));
      sum += gg[lv][i];
    }
    for (int i = 0; i < k; ++i) gg[lv][i] /= sum;
  }

  G157 gw;
  for (int i = 0; i < 3; ++i) gw.g3[i] = (float)gg[0][i];
  for (int i = 0; i < 5; ++i) gw.g5[i] = (float)gg[1][i];
  for (int i = 0; i < 7; ++i) gw.g7[i] = (float)gg[2][i];

  WC wc;
  {
    double t35[7] = {0};
    for (int i = 0; i < 3; ++i)
      for (int j = 0; j < 5; ++j) t35[i + j] += gg[0][i] * gg[1][j];
    double t357[13] = {0};
    for (int i = 0; i < 7; ++i)
      for (int j = 0; j < 7; ++j) t357[i + j] += t35[i] * gg[2][j];
    for (int t = 0; t < 13; ++t) wc.c[t] = (float)t357[t];
  }

  zero_k<<<dim3(256), dim3(256), 0, stream>>>(out, S, wtab, gw);
  ctx_k<<<dim3(4096), dim3(256), 0, stream>>>(x, ctxb, wtab, wc);
  att_k<<<dim3(64, 16), dim3(256), 0, stream>>>(ctxb, S, out);
  fin_k<<<dim3(256), dim3(256), 0, stream>>>(out, S);
}